// Round 2
// baseline (339.699 us; speedup 1.0000x reference)
//
#include <hip/hip_runtime.h>
#include <math.h>

#define T_DIM 4096
#define TRACE 64
#define CTX   64
#define NELEM  (T_DIM * TRACE * CTX)   // 16,777,216 floats per tensor
#define NGROUP (NELEM / 4)             // 4,194,304 float4 groups

typedef float f32x4 __attribute__((ext_vector_type(4)));  // native vector for nt-store

// ---------------------------------------------------------------------------
// Kernel A: precompute per-t trig/decay tables (3 MB total, L2/L3 resident).
// Removes ALL transcendentals (large-arg sincosf slow path!) from the
// streaming kernel's critical path. Also writes the counter output.
// TRACE == CTX == 64, so one [T*64] index covers all three tables.
// ---------------------------------------------------------------------------
__global__ __launch_bounds__(256) void ffm_tables(
    const float* __restrict__ a, const float* __restrict__ b,
    const int*   __restrict__ iv, const int* __restrict__ jv,
    float* __restrict__ tcos, float* __restrict__ tsin,
    float* __restrict__ tdec, float* __restrict__ out_cnt)
{
    const int idx = blockIdx.x * 256 + threadIdx.x;  // 0 .. T*64-1
    const int t   = idx >> 6;
    const int k   = idx & 63;
    const float tf = (float)jv[t];
    float s, c;
    sincosf(b[k] * tf, &s, &c);        // accurate; fully parallel here
    tcos[idx] = c;
    tsin[idx] = s;
    tdec[idx] = expf(-fabsf(a[k]) * tf);
    if (k == 0) out_cnt[t] = (float)(jv[t] + iv[t]);
}

// ---------------------------------------------------------------------------
// Kernel B: pure streaming elementwise — no LDS, no barrier, grid-stride.
// Per float4 group: 2 table float4 loads + 1 scalar (L2-hit), 4 streaming
// float4 loads, 16 FMA, 2 nontemporal float4 stores (don't evict L3 inputs).
// ---------------------------------------------------------------------------
__global__ __launch_bounds__(256) void ffm_main(
    const float* __restrict__ sre_, const float* __restrict__ sim_,
    const float* __restrict__ xre_, const float* __restrict__ xim_,
    const float* __restrict__ tcos, const float* __restrict__ tsin,
    const float* __restrict__ tdec,
    float* __restrict__ out)
{
    const float4* __restrict__ sre = (const float4*)sre_;
    const float4* __restrict__ sim = (const float4*)sim_;
    const float4* __restrict__ xre = (const float4*)xre_;
    const float4* __restrict__ xim = (const float4*)xim_;
    f32x4* __restrict__ o = (f32x4*)out;

    const int stride = gridDim.x * 256;              // 2048*256 = 524288
    const int g0 = blockIdx.x * 256 + threadIdx.x;

    #pragma unroll 2
    for (int it = 0; it < NGROUP / (2048 * 256); ++it) {   // exactly 8 trips
        const int g  = g0 + it * stride;
        const int e  = g << 2;                // element index
        const int t  = e >> 12;               // 4096 elems per t
        const int tr = (e >> 6) & 63;         // trace row (16 lanes share)
        const int c0 = e & 63;                // ctx start, multiple of 4

        // Table loads (independent, issue first; wave-uniform t => L1/L2 hits)
        const float4 vc  = *(const float4*)(tcos + t * 64 + c0);
        const float4 vs  = *(const float4*)(tsin + t * 64 + c0);
        const float  dec = tdec[t * 64 + tr];

        // Streaming loads
        const float4 vre = sre[g];
        const float4 vim = sim[g];
        const float4 vxr = xre[g];
        const float4 vxi = xim[g];

        const float gr0 = dec * vc.x, gi0 = dec * vs.x;
        const float gr1 = dec * vc.y, gi1 = dec * vs.y;
        const float gr2 = dec * vc.z, gi2 = dec * vs.z;
        const float gr3 = dec * vc.w, gi3 = dec * vs.w;

        f32x4 o0, o1;
        o0.x = fmaf(vre.x, gr0, fmaf(-vim.x, gi0, vxr.x));
        o0.y = fmaf(vre.x, gi0, fmaf( vim.x, gr0, vxi.x));
        o0.z = fmaf(vre.y, gr1, fmaf(-vim.y, gi1, vxr.y));
        o0.w = fmaf(vre.y, gi1, fmaf( vim.y, gr1, vxi.y));
        o1.x = fmaf(vre.z, gr2, fmaf(-vim.z, gi2, vxr.z));
        o1.y = fmaf(vre.z, gi2, fmaf( vim.z, gr2, vxi.z));
        o1.z = fmaf(vre.w, gr3, fmaf(-vim.w, gi3, vxr.w));
        o1.w = fmaf(vre.w, gi3, fmaf( vim.w, gr3, vxi.w));

        __builtin_nontemporal_store(o0, &o[2 * g + 0]);
        __builtin_nontemporal_store(o1, &o[2 * g + 1]);
    }
}

// ---------------------------------------------------------------------------
// Fallback (workspace too small): previous single-kernel version.
// ---------------------------------------------------------------------------
__global__ __launch_bounds__(256) void ffm_kernel_fallback(
    const float* __restrict__ state_re, const float* __restrict__ state_im,
    const float* __restrict__ x_re, const float* __restrict__ x_im,
    const float* __restrict__ a, const float* __restrict__ b,
    const int* __restrict__ ivec, const int* __restrict__ jvec,
    float* __restrict__ out, float* __restrict__ out_cnt)
{
    const int t   = blockIdx.x;
    const int tid = threadIdx.x;
    const float tf = (float)jvec[t];

    __shared__ float s_cos[CTX];
    __shared__ float s_sin[CTX];
    __shared__ float s_dec[TRACE];

    if (tid < CTX) {
        float theta = b[tid] * tf;
        float s, c;
        sincosf(theta, &s, &c);
        s_cos[tid] = c;
        s_sin[tid] = s;
    } else if (tid < CTX + TRACE) {
        int tr = tid - CTX;
        s_dec[tr] = expf(-fabsf(a[tr]) * tf);
    }
    if (tid == 0) out_cnt[t] = (float)(jvec[t] + ivec[t]);
    __syncthreads();

    const size_t base = (size_t)t * (TRACE * CTX);
    const float4* sre = (const float4*)(state_re + base);
    const float4* sim = (const float4*)(state_im + base);
    const float4* xre = (const float4*)(x_re + base);
    const float4* xim = (const float4*)(x_im + base);
    float4* o = (float4*)(out + base * 2);

    #pragma unroll
    for (int k = 0; k < 4; ++k) {
        const int g  = tid + k * 256;
        const int e  = g * 4;
        const int tr = e >> 6;
        const int c0 = e & 63;

        const float dec = s_dec[tr];
        const float4 vre = sre[g];
        const float4 vim = sim[g];
        const float4 vxr = xre[g];
        const float4 vxi = xim[g];

        const float gr0 = dec * s_cos[c0 + 0], gi0 = dec * s_sin[c0 + 0];
        const float gr1 = dec * s_cos[c0 + 1], gi1 = dec * s_sin[c0 + 1];
        const float gr2 = dec * s_cos[c0 + 2], gi2 = dec * s_sin[c0 + 2];
        const float gr3 = dec * s_cos[c0 + 3], gi3 = dec * s_sin[c0 + 3];

        float4 o0, o1;
        o0.x = fmaf(vre.x, gr0, fmaf(-vim.x, gi0, vxr.x));
        o0.y = fmaf(vre.x, gi0, fmaf( vim.x, gr0, vxi.x));
        o0.z = fmaf(vre.y, gr1, fmaf(-vim.y, gi1, vxr.y));
        o0.w = fmaf(vre.y, gi1, fmaf( vim.y, gr1, vxi.y));
        o1.x = fmaf(vre.z, gr2, fmaf(-vim.z, gi2, vxr.z));
        o1.y = fmaf(vre.z, gi2, fmaf( vim.z, gr2, vxi.z));
        o1.z = fmaf(vre.w, gr3, fmaf(-vim.w, gi3, vxr.w));
        o1.w = fmaf(vre.w, gi3, fmaf( vim.w, gr3, vxi.w));

        o[2 * g + 0] = o0;
        o[2 * g + 1] = o1;
    }
}

extern "C" void kernel_launch(void* const* d_in, const int* in_sizes, int n_in,
                              void* d_out, int out_size, void* d_ws, size_t ws_size,
                              hipStream_t stream) {
    const float* state_re = (const float*)d_in[0];
    const float* state_im = (const float*)d_in[1];
    const float* x_re     = (const float*)d_in[2];
    const float* x_im     = (const float*)d_in[3];
    const float* a        = (const float*)d_in[4];
    const float* b        = (const float*)d_in[5];
    const int*   iv       = (const int*)d_in[6];
    const int*   jv       = (const int*)d_in[7];

    float* out     = (float*)d_out;
    float* out_cnt = out + (size_t)T_DIM * TRACE * CTX * 2;

    const size_t tab_elems = (size_t)T_DIM * 64;       // 262144 per table
    const size_t need = 3 * tab_elems * sizeof(float); // 3 MB

    if (ws_size >= need) {
        float* tcos = (float*)d_ws;
        float* tsin = tcos + tab_elems;
        float* tdec = tsin + tab_elems;

        ffm_tables<<<T_DIM * 64 / 256, 256, 0, stream>>>(
            a, b, iv, jv, tcos, tsin, tdec, out_cnt);
        ffm_main<<<2048, 256, 0, stream>>>(
            state_re, state_im, x_re, x_im, tcos, tsin, tdec, out);
    } else {
        ffm_kernel_fallback<<<T_DIM, 256, 0, stream>>>(
            state_re, state_im, x_re, x_im, a, b, iv, jv, out, out_cnt);
    }
}

// Round 3
// 329.701 us; speedup vs baseline: 1.0303x; 1.0303x over previous
//
#include <hip/hip_runtime.h>
#include <math.h>

#define T_DIM 4096
#define TRACE 64
#define CTX   64

// ---------------------------------------------------------------------------
// Kernel A: precompute per-t trig/decay tables (3 MB total, L2/L3 resident).
// Removes all transcendentals (large-arg sincosf slow path) from the
// streaming kernel. Also writes the counter output.
// ---------------------------------------------------------------------------
__global__ __launch_bounds__(256) void ffm_tables(
    const float* __restrict__ a, const float* __restrict__ b,
    const int*   __restrict__ iv, const int* __restrict__ jv,
    float* __restrict__ tcos, float* __restrict__ tsin,
    float* __restrict__ tdec, float* __restrict__ out_cnt)
{
    const int idx = blockIdx.x * 256 + threadIdx.x;  // 0 .. T*64-1
    const int t   = idx >> 6;
    const int k   = idx & 63;
    const float tf = (float)jv[t];
    float s, c;
    sincosf(b[k] * tf, &s, &c);
    tcos[idx] = c;
    tsin[idx] = s;
    tdec[idx] = expf(-fabsf(a[k]) * tf);
    if (k == 0) out_cnt[t] = (float)(jv[t] + iv[t]);
}

// ---------------------------------------------------------------------------
// Kernel B: EXACT baseline memory structure (one block per t, 4 float4 groups
// per thread, normal stores) — only change vs the 113 us baseline: trig/decay
// come from the precomputed global tables (L1-hit float4 loads) instead of an
// LDS prologue. No barrier, no LDS, no transcendentals.
// ---------------------------------------------------------------------------
__global__ __launch_bounds__(256) void ffm_main(
    const float* __restrict__ state_re, const float* __restrict__ state_im,
    const float* __restrict__ x_re, const float* __restrict__ x_im,
    const float* __restrict__ tcos, const float* __restrict__ tsin,
    const float* __restrict__ tdec,
    float* __restrict__ out)
{
    const int t   = blockIdx.x;
    const int tid = threadIdx.x;

    const size_t base = (size_t)t * (TRACE * CTX);
    const float4* sre = (const float4*)(state_re + base);
    const float4* sim = (const float4*)(state_im + base);
    const float4* xre = (const float4*)(x_re + base);
    const float4* xim = (const float4*)(x_im + base);
    float4* o = (float4*)(out + base * 2);

    const float4* tc = (const float4*)(tcos + t * 64);
    const float4* ts = (const float4*)(tsin + t * 64);
    const float*  td = tdec + t * 64;

    // 4096 elements per t = 1024 float4 groups; 256 threads -> 4 groups each.
    #pragma unroll
    for (int k = 0; k < 4; ++k) {
        const int g  = tid + k * 256;   // float4 group index, 0..1023
        const int e  = g * 4;           // element index within [TRACE*CTX]
        const int tr = e >> 6;          // trace row (all 4 elems share it)
        const int c4 = (e & 63) >> 2;   // ctx float4 index, 0..15

        // Table loads: 16 distinct addrs per wave -> L1 broadcast hits
        const float  dec = td[tr];
        const float4 vc  = tc[c4];
        const float4 vs  = ts[c4];

        const float4 vre = sre[g];
        const float4 vim = sim[g];
        const float4 vxr = xre[g];
        const float4 vxi = xim[g];

        const float gr0 = dec * vc.x, gi0 = dec * vs.x;
        const float gr1 = dec * vc.y, gi1 = dec * vs.y;
        const float gr2 = dec * vc.z, gi2 = dec * vs.z;
        const float gr3 = dec * vc.w, gi3 = dec * vs.w;

        float4 o0, o1;
        o0.x = fmaf(vre.x, gr0, fmaf(-vim.x, gi0, vxr.x));
        o0.y = fmaf(vre.x, gi0, fmaf( vim.x, gr0, vxi.x));
        o0.z = fmaf(vre.y, gr1, fmaf(-vim.y, gi1, vxr.y));
        o0.w = fmaf(vre.y, gi1, fmaf( vim.y, gr1, vxi.y));
        o1.x = fmaf(vre.z, gr2, fmaf(-vim.z, gi2, vxr.z));
        o1.y = fmaf(vre.z, gi2, fmaf( vim.z, gr2, vxi.z));
        o1.z = fmaf(vre.w, gr3, fmaf(-vim.w, gi3, vxr.w));
        o1.w = fmaf(vre.w, gi3, fmaf( vim.w, gr3, vxi.w));

        o[2 * g + 0] = o0;   // normal stores: L2 write-combines the pair
        o[2 * g + 1] = o1;
    }
}

// ---------------------------------------------------------------------------
// Fallback (workspace too small): original single-kernel version.
// ---------------------------------------------------------------------------
__global__ __launch_bounds__(256) void ffm_kernel_fallback(
    const float* __restrict__ state_re, const float* __restrict__ state_im,
    const float* __restrict__ x_re, const float* __restrict__ x_im,
    const float* __restrict__ a, const float* __restrict__ b,
    const int* __restrict__ ivec, const int* __restrict__ jvec,
    float* __restrict__ out, float* __restrict__ out_cnt)
{
    const int t   = blockIdx.x;
    const int tid = threadIdx.x;
    const float tf = (float)jvec[t];

    __shared__ float s_cos[CTX];
    __shared__ float s_sin[CTX];
    __shared__ float s_dec[TRACE];

    if (tid < CTX) {
        float theta = b[tid] * tf;
        float s, c;
        sincosf(theta, &s, &c);
        s_cos[tid] = c;
        s_sin[tid] = s;
    } else if (tid < CTX + TRACE) {
        int tr = tid - CTX;
        s_dec[tr] = expf(-fabsf(a[tr]) * tf);
    }
    if (tid == 0) out_cnt[t] = (float)(jvec[t] + ivec[t]);
    __syncthreads();

    const size_t base = (size_t)t * (TRACE * CTX);
    const float4* sre = (const float4*)(state_re + base);
    const float4* sim = (const float4*)(state_im + base);
    const float4* xre = (const float4*)(x_re + base);
    const float4* xim = (const float4*)(x_im + base);
    float4* o = (float4*)(out + base * 2);

    #pragma unroll
    for (int k = 0; k < 4; ++k) {
        const int g  = tid + k * 256;
        const int e  = g * 4;
        const int tr = e >> 6;
        const int c0 = e & 63;

        const float dec = s_dec[tr];
        const float4 vre = sre[g];
        const float4 vim = sim[g];
        const float4 vxr = xre[g];
        const float4 vxi = xim[g];

        const float gr0 = dec * s_cos[c0 + 0], gi0 = dec * s_sin[c0 + 0];
        const float gr1 = dec * s_cos[c0 + 1], gi1 = dec * s_sin[c0 + 1];
        const float gr2 = dec * s_cos[c0 + 2], gi2 = dec * s_sin[c0 + 2];
        const float gr3 = dec * s_cos[c0 + 3], gi3 = dec * s_sin[c0 + 3];

        float4 o0, o1;
        o0.x = fmaf(vre.x, gr0, fmaf(-vim.x, gi0, vxr.x));
        o0.y = fmaf(vre.x, gi0, fmaf( vim.x, gr0, vxi.x));
        o0.z = fmaf(vre.y, gr1, fmaf(-vim.y, gi1, vxr.y));
        o0.w = fmaf(vre.y, gi1, fmaf( vim.y, gr1, vxi.y));
        o1.x = fmaf(vre.z, gr2, fmaf(-vim.z, gi2, vxr.z));
        o1.y = fmaf(vre.z, gi2, fmaf( vim.z, gr2, vxi.z));
        o1.z = fmaf(vre.w, gr3, fmaf(-vim.w, gi3, vxr.w));
        o1.w = fmaf(vre.w, gi3, fmaf( vim.w, gr3, vxi.w));

        o[2 * g + 0] = o0;
        o[2 * g + 1] = o1;
    }
}

extern "C" void kernel_launch(void* const* d_in, const int* in_sizes, int n_in,
                              void* d_out, int out_size, void* d_ws, size_t ws_size,
                              hipStream_t stream) {
    const float* state_re = (const float*)d_in[0];
    const float* state_im = (const float*)d_in[1];
    const float* x_re     = (const float*)d_in[2];
    const float* x_im     = (const float*)d_in[3];
    const float* a        = (const float*)d_in[4];
    const float* b        = (const float*)d_in[5];
    const int*   iv       = (const int*)d_in[6];
    const int*   jv       = (const int*)d_in[7];

    float* out     = (float*)d_out;
    float* out_cnt = out + (size_t)T_DIM * TRACE * CTX * 2;

    const size_t tab_elems = (size_t)T_DIM * 64;       // 262144 per table
    const size_t need = 3 * tab_elems * sizeof(float); // 3 MB

    if (ws_size >= need) {
        float* tcos = (float*)d_ws;
        float* tsin = tcos + tab_elems;
        float* tdec = tsin + tab_elems;

        ffm_tables<<<T_DIM * 64 / 256, 256, 0, stream>>>(
            a, b, iv, jv, tcos, tsin, tdec, out_cnt);
        ffm_main<<<T_DIM, 256, 0, stream>>>(
            state_re, state_im, x_re, x_im, tcos, tsin, tdec, out);
    } else {
        ffm_kernel_fallback<<<T_DIM, 256, 0, stream>>>(
            state_re, state_im, x_re, x_im, a, b, iv, jv, out, out_cnt);
    }
}

// Round 4
// 329.450 us; speedup vs baseline: 1.0311x; 1.0008x over previous
//
#include <hip/hip_runtime.h>
#include <math.h>

#define T_DIM 4096
#define TRACE 64
#define CTX   64

// ---------------------------------------------------------------------------
// Kernel A: precompute per-t trig/decay tables (3 MB, L2/L3 resident).
// ---------------------------------------------------------------------------
__global__ __launch_bounds__(256) void ffm_tables(
    const float* __restrict__ a, const float* __restrict__ b,
    const int*   __restrict__ iv, const int* __restrict__ jv,
    float* __restrict__ tcos, float* __restrict__ tsin,
    float* __restrict__ tdec, float* __restrict__ out_cnt)
{
    const int idx = blockIdx.x * 256 + threadIdx.x;  // 0 .. T*64-1
    const int t   = idx >> 6;
    const int k   = idx & 63;
    const float tf = (float)jv[t];
    float s, c;
    sincosf(b[k] * tf, &s, &c);
    tcos[idx] = c;
    tsin[idx] = s;
    tdec[idx] = expf(-fabsf(a[k]) * tf);
    if (k == 0) out_cnt[t] = (float)(jv[t] + iv[t]);
}

// ---------------------------------------------------------------------------
// Kernel B: same block/t mapping as the 113-116 us versions, but ALL loads
// (16 streaming float4 + tables) are issued as one batch before any compute,
// pinned by sched_barrier(0). Per wave: 16 KB in flight, 4 KB contiguous per
// stream -> max MLP + DRAM-page-friendly chunking. launch_bounds(256,4)
// allows up to 128 VGPRs while keeping 4 blocks/CU.
// ---------------------------------------------------------------------------
__global__ __launch_bounds__(256, 4) void ffm_main(
    const float* __restrict__ state_re, const float* __restrict__ state_im,
    const float* __restrict__ x_re, const float* __restrict__ x_im,
    const float* __restrict__ tcos, const float* __restrict__ tsin,
    const float* __restrict__ tdec,
    float* __restrict__ out)
{
    const int t   = blockIdx.x;
    const int tid = threadIdx.x;

    const size_t base = (size_t)t * (TRACE * CTX);
    const float4* __restrict__ sre = (const float4*)(state_re + base);
    const float4* __restrict__ sim = (const float4*)(state_im + base);
    const float4* __restrict__ xre = (const float4*)(x_re + base);
    const float4* __restrict__ xim = (const float4*)(x_im + base);
    float4* __restrict__ o = (float4*)(out + base * 2);

    const float4* __restrict__ tc = (const float4*)(tcos + t * 64);
    const float4* __restrict__ ts = (const float4*)(tsin + t * 64);
    const float*  __restrict__ td = tdec + t * 64;

    // ---- load phase: 16 streaming loads + 12 table loads, no compute ----
    float4 vre[4], vim[4], vxr[4], vxi[4], vc[4], vs[4];
    float  dec[4];

    #pragma unroll
    for (int k = 0; k < 4; ++k) vre[k] = sre[tid + k * 256];
    #pragma unroll
    for (int k = 0; k < 4; ++k) vim[k] = sim[tid + k * 256];
    #pragma unroll
    for (int k = 0; k < 4; ++k) vxr[k] = xre[tid + k * 256];
    #pragma unroll
    for (int k = 0; k < 4; ++k) vxi[k] = xim[tid + k * 256];
    #pragma unroll
    for (int k = 0; k < 4; ++k) {
        const int g = tid + k * 256;        // float4 group, 0..1023
        vc[k]  = tc[g & 15];                // ctx float4 (16/row)
        vs[k]  = ts[g & 15];
        dec[k] = td[g >> 4];                // trace row (64 groups/16 = row)
    }
    __builtin_amdgcn_sched_barrier(0);      // keep loads clustered above

    // ---- compute + store phase ----
    #pragma unroll
    for (int k = 0; k < 4; ++k) {
        const int g = tid + k * 256;

        const float gr0 = dec[k] * vc[k].x, gi0 = dec[k] * vs[k].x;
        const float gr1 = dec[k] * vc[k].y, gi1 = dec[k] * vs[k].y;
        const float gr2 = dec[k] * vc[k].z, gi2 = dec[k] * vs[k].z;
        const float gr3 = dec[k] * vc[k].w, gi3 = dec[k] * vs[k].w;

        float4 o0, o1;
        o0.x = fmaf(vre[k].x, gr0, fmaf(-vim[k].x, gi0, vxr[k].x));
        o0.y = fmaf(vre[k].x, gi0, fmaf( vim[k].x, gr0, vxi[k].x));
        o0.z = fmaf(vre[k].y, gr1, fmaf(-vim[k].y, gi1, vxr[k].y));
        o0.w = fmaf(vre[k].y, gi1, fmaf( vim[k].y, gr1, vxi[k].y));
        o1.x = fmaf(vre[k].z, gr2, fmaf(-vim[k].z, gi2, vxr[k].z));
        o1.y = fmaf(vre[k].z, gi2, fmaf( vim[k].z, gr2, vxi[k].z));
        o1.z = fmaf(vre[k].w, gr3, fmaf(-vim[k].w, gi3, vxr[k].w));
        o1.w = fmaf(vre[k].w, gi3, fmaf( vim[k].w, gr3, vxi[k].w));

        o[2 * g + 0] = o0;
        o[2 * g + 1] = o1;
    }
}

// ---------------------------------------------------------------------------
// Fallback (workspace too small): original single-kernel version.
// ---------------------------------------------------------------------------
__global__ __launch_bounds__(256) void ffm_kernel_fallback(
    const float* __restrict__ state_re, const float* __restrict__ state_im,
    const float* __restrict__ x_re, const float* __restrict__ x_im,
    const float* __restrict__ a, const float* __restrict__ b,
    const int* __restrict__ ivec, const int* __restrict__ jvec,
    float* __restrict__ out, float* __restrict__ out_cnt)
{
    const int t   = blockIdx.x;
    const int tid = threadIdx.x;
    const float tf = (float)jvec[t];

    __shared__ float s_cos[CTX];
    __shared__ float s_sin[CTX];
    __shared__ float s_dec[TRACE];

    if (tid < CTX) {
        float theta = b[tid] * tf;
        float s, c;
        sincosf(theta, &s, &c);
        s_cos[tid] = c;
        s_sin[tid] = s;
    } else if (tid < CTX + TRACE) {
        int tr = tid - CTX;
        s_dec[tr] = expf(-fabsf(a[tr]) * tf);
    }
    if (tid == 0) out_cnt[t] = (float)(jvec[t] + ivec[t]);
    __syncthreads();

    const size_t base = (size_t)t * (TRACE * CTX);
    const float4* sre = (const float4*)(state_re + base);
    const float4* sim = (const float4*)(state_im + base);
    const float4* xre = (const float4*)(x_re + base);
    const float4* xim = (const float4*)(x_im + base);
    float4* o = (float4*)(out + base * 2);

    #pragma unroll
    for (int k = 0; k < 4; ++k) {
        const int g  = tid + k * 256;
        const int e  = g * 4;
        const int tr = e >> 6;
        const int c0 = e & 63;

        const float dec = s_dec[tr];
        const float4 vre = sre[g];
        const float4 vim = sim[g];
        const float4 vxr = xre[g];
        const float4 vxi = xim[g];

        const float gr0 = dec * s_cos[c0 + 0], gi0 = dec * s_sin[c0 + 0];
        const float gr1 = dec * s_cos[c0 + 1], gi1 = dec * s_sin[c0 + 1];
        const float gr2 = dec * s_cos[c0 + 2], gi2 = dec * s_sin[c0 + 2];
        const float gr3 = dec * s_cos[c0 + 3], gi3 = dec * s_sin[c0 + 3];

        float4 o0, o1;
        o0.x = fmaf(vre.x, gr0, fmaf(-vim.x, gi0, vxr.x));
        o0.y = fmaf(vre.x, gi0, fmaf( vim.x, gr0, vxi.x));
        o0.z = fmaf(vre.y, gr1, fmaf(-vim.y, gi1, vxr.y));
        o0.w = fmaf(vre.y, gi1, fmaf( vim.y, gr1, vxi.y));
        o1.x = fmaf(vre.z, gr2, fmaf(-vim.z, gi2, vxr.z));
        o1.y = fmaf(vre.z, gi2, fmaf( vim.z, gr2, vxi.z));
        o1.z = fmaf(vre.w, gr3, fmaf(-vim.w, gi3, vxr.w));
        o1.w = fmaf(vre.w, gi3, fmaf( vim.w, gr3, vxi.w));

        o[2 * g + 0] = o0;
        o[2 * g + 1] = o1;
    }
}

extern "C" void kernel_launch(void* const* d_in, const int* in_sizes, int n_in,
                              void* d_out, int out_size, void* d_ws, size_t ws_size,
                              hipStream_t stream) {
    const float* state_re = (const float*)d_in[0];
    const float* state_im = (const float*)d_in[1];
    const float* x_re     = (const float*)d_in[2];
    const float* x_im     = (const float*)d_in[3];
    const float* a        = (const float*)d_in[4];
    const float* b        = (const float*)d_in[5];
    const int*   iv       = (const int*)d_in[6];
    const int*   jv       = (const int*)d_in[7];

    float* out     = (float*)d_out;
    float* out_cnt = out + (size_t)T_DIM * TRACE * CTX * 2;

    const size_t tab_elems = (size_t)T_DIM * 64;       // 262144 per table
    const size_t need = 3 * tab_elems * sizeof(float); // 3 MB

    if (ws_size >= need) {
        float* tcos = (float*)d_ws;
        float* tsin = tcos + tab_elems;
        float* tdec = tsin + tab_elems;

        ffm_tables<<<T_DIM * 64 / 256, 256, 0, stream>>>(
            a, b, iv, jv, tcos, tsin, tdec, out_cnt);
        ffm_main<<<T_DIM, 256, 0, stream>>>(
            state_re, state_im, x_re, x_im, tcos, tsin, tdec, out);
    } else {
        ffm_kernel_fallback<<<T_DIM, 256, 0, stream>>>(
            state_re, state_im, x_re, x_im, a, b, iv, jv, out, out_cnt);
    }
}

// Round 5
// 326.676 us; speedup vs baseline: 1.0399x; 1.0085x over previous
//
#include <hip/hip_runtime.h>
#include <math.h>

#define T_DIM 4096
#define TRACE 64
#define CTX   64

// ---------------------------------------------------------------------------
// Kernel A: precompute per-t trig/decay tables (3 MB, L2/L3 resident).
// ---------------------------------------------------------------------------
__global__ __launch_bounds__(256) void ffm_tables(
    const float* __restrict__ a, const float* __restrict__ b,
    const int*   __restrict__ iv, const int* __restrict__ jv,
    float* __restrict__ tcos, float* __restrict__ tsin,
    float* __restrict__ tdec, float* __restrict__ out_cnt)
{
    const int idx = blockIdx.x * 256 + threadIdx.x;  // 0 .. T*64-1
    const int t   = idx >> 6;
    const int k   = idx & 63;
    const float tf = (float)jv[t];
    float s, c;
    sincosf(b[k] * tf, &s, &c);
    tcos[idx] = c;
    tsin[idx] = s;
    tdec[idx] = expf(-fabsf(a[k]) * tf);
    if (k == 0) out_cnt[t] = (float)(jv[t] + iv[t]);
}

// ---------------------------------------------------------------------------
// Kernel B: burst-shaped streaming.
//   g = w*256 + k*64 + lane  -> each wave reads a CONTIGUOUS 4 KB run per
//   input stream (k=0..3) and writes a contiguous 8 KB output run, instead
//   of 4x1KB chunks strided 4KB apart. Stream issue order is rotated per
//   wave (wave w starts at stream w) to decorrelate the instantaneous
//   channel footprint across the chip's waves.
//   Table loads collapse: vc/vs are loop-invariant (lane&15).
// ---------------------------------------------------------------------------
__global__ __launch_bounds__(256) void ffm_main(
    const float* __restrict__ state_re, const float* __restrict__ state_im,
    const float* __restrict__ x_re, const float* __restrict__ x_im,
    const float* __restrict__ tcos, const float* __restrict__ tsin,
    const float* __restrict__ tdec,
    float* __restrict__ out)
{
    const int t    = blockIdx.x;
    const int tid  = threadIdx.x;
    const int w    = tid >> 6;          // wave 0..3
    const int lane = tid & 63;
    const int g0   = w * 256 + lane;    // wave-contiguous base group

    const size_t base = (size_t)t * (TRACE * CTX);
    const float4* __restrict__ sre = (const float4*)(state_re + base);
    const float4* __restrict__ sim = (const float4*)(state_im + base);
    const float4* __restrict__ xre = (const float4*)(x_re + base);
    const float4* __restrict__ xim = (const float4*)(x_im + base);
    float4* __restrict__ o = (float4*)(out + base * 2);

    // Tables: vc/vs identical for all k (g & 15 == lane & 15).
    const float4 vc = ((const float4*)(tcos + t * 64))[lane & 15];
    const float4 vs = ((const float4*)(tsin + t * 64))[lane & 15];
    const float* td = tdec + t * 64;
    float dec[4];
    #pragma unroll
    for (int k = 0; k < 4; ++k)
        dec[k] = td[w * 16 + k * 4 + (lane >> 4)];   // tr = g>>4

    // Stream loads: contiguous 4KB per stream per wave, order rotated by w.
    float4 vre[4], vim[4], vxr[4], vxi[4];
#define LD4(dst, src) \
    dst[0] = src[g0]; dst[1] = src[g0 + 64]; \
    dst[2] = src[g0 + 128]; dst[3] = src[g0 + 192];
    switch (w) {
      case 0: LD4(vre, sre) LD4(vim, sim) LD4(vxr, xre) LD4(vxi, xim) break;
      case 1: LD4(vim, sim) LD4(vxr, xre) LD4(vxi, xim) LD4(vre, sre) break;
      case 2: LD4(vxr, xre) LD4(vxi, xim) LD4(vre, sre) LD4(vim, sim) break;
      default: LD4(vxi, xim) LD4(vre, sre) LD4(vim, sim) LD4(vxr, xre) break;
    }
#undef LD4

    #pragma unroll
    for (int k = 0; k < 4; ++k) {
        const int g = g0 + k * 64;

        const float gr0 = dec[k] * vc.x, gi0 = dec[k] * vs.x;
        const float gr1 = dec[k] * vc.y, gi1 = dec[k] * vs.y;
        const float gr2 = dec[k] * vc.z, gi2 = dec[k] * vs.z;
        const float gr3 = dec[k] * vc.w, gi3 = dec[k] * vs.w;

        float4 o0, o1;
        o0.x = fmaf(vre[k].x, gr0, fmaf(-vim[k].x, gi0, vxr[k].x));
        o0.y = fmaf(vre[k].x, gi0, fmaf( vim[k].x, gr0, vxi[k].x));
        o0.z = fmaf(vre[k].y, gr1, fmaf(-vim[k].y, gi1, vxr[k].y));
        o0.w = fmaf(vre[k].y, gi1, fmaf( vim[k].y, gr1, vxi[k].y));
        o1.x = fmaf(vre[k].z, gr2, fmaf(-vim[k].z, gi2, vxr[k].z));
        o1.y = fmaf(vre[k].z, gi2, fmaf( vim[k].z, gr2, vxi[k].z));
        o1.z = fmaf(vre[k].w, gr3, fmaf(-vim[k].w, gi3, vxr[k].w));
        o1.w = fmaf(vre[k].w, gi3, fmaf( vim[k].w, gr3, vxi[k].w));

        o[2 * g + 0] = o0;
        o[2 * g + 1] = o1;
    }
}

// ---------------------------------------------------------------------------
// Fallback (workspace too small): original single-kernel version.
// ---------------------------------------------------------------------------
__global__ __launch_bounds__(256) void ffm_kernel_fallback(
    const float* __restrict__ state_re, const float* __restrict__ state_im,
    const float* __restrict__ x_re, const float* __restrict__ x_im,
    const float* __restrict__ a, const float* __restrict__ b,
    const int* __restrict__ ivec, const int* __restrict__ jvec,
    float* __restrict__ out, float* __restrict__ out_cnt)
{
    const int t   = blockIdx.x;
    const int tid = threadIdx.x;
    const float tf = (float)jvec[t];

    __shared__ float s_cos[CTX];
    __shared__ float s_sin[CTX];
    __shared__ float s_dec[TRACE];

    if (tid < CTX) {
        float theta = b[tid] * tf;
        float s, c;
        sincosf(theta, &s, &c);
        s_cos[tid] = c;
        s_sin[tid] = s;
    } else if (tid < CTX + TRACE) {
        int tr = tid - CTX;
        s_dec[tr] = expf(-fabsf(a[tr]) * tf);
    }
    if (tid == 0) out_cnt[t] = (float)(jvec[t] + ivec[t]);
    __syncthreads();

    const size_t base = (size_t)t * (TRACE * CTX);
    const float4* sre = (const float4*)(state_re + base);
    const float4* sim = (const float4*)(state_im + base);
    const float4* xre = (const float4*)(x_re + base);
    const float4* xim = (const float4*)(x_im + base);
    float4* o = (float4*)(out + base * 2);

    #pragma unroll
    for (int k = 0; k < 4; ++k) {
        const int g  = tid + k * 256;
        const int e  = g * 4;
        const int tr = e >> 6;
        const int c0 = e & 63;

        const float dec = s_dec[tr];
        const float4 vre = sre[g];
        const float4 vim = sim[g];
        const float4 vxr = xre[g];
        const float4 vxi = xim[g];

        const float gr0 = dec * s_cos[c0 + 0], gi0 = dec * s_sin[c0 + 0];
        const float gr1 = dec * s_cos[c0 + 1], gi1 = dec * s_sin[c0 + 1];
        const float gr2 = dec * s_cos[c0 + 2], gi2 = dec * s_sin[c0 + 2];
        const float gr3 = dec * s_cos[c0 + 3], gi3 = dec * s_sin[c0 + 3];

        float4 o0, o1;
        o0.x = fmaf(vre.x, gr0, fmaf(-vim.x, gi0, vxr.x));
        o0.y = fmaf(vre.x, gi0, fmaf( vim.x, gr0, vxi.x));
        o0.z = fmaf(vre.y, gr1, fmaf(-vim.y, gi1, vxr.y));
        o0.w = fmaf(vre.y, gi1, fmaf( vim.y, gr1, vxi.y));
        o1.x = fmaf(vre.z, gr2, fmaf(-vim.z, gi2, vxr.z));
        o1.y = fmaf(vre.z, gi2, fmaf( vim.z, gr2, vxi.z));
        o1.z = fmaf(vre.w, gr3, fmaf(-vim.w, gi3, vxr.w));
        o1.w = fmaf(vre.w, gi3, fmaf( vim.w, gr3, vxi.w));

        o[2 * g + 0] = o0;
        o[2 * g + 1] = o1;
    }
}

extern "C" void kernel_launch(void* const* d_in, const int* in_sizes, int n_in,
                              void* d_out, int out_size, void* d_ws, size_t ws_size,
                              hipStream_t stream) {
    const float* state_re = (const float*)d_in[0];
    const float* state_im = (const float*)d_in[1];
    const float* x_re     = (const float*)d_in[2];
    const float* x_im     = (const float*)d_in[3];
    const float* a        = (const float*)d_in[4];
    const float* b        = (const float*)d_in[5];
    const int*   iv       = (const int*)d_in[6];
    const int*   jv       = (const int*)d_in[7];

    float* out     = (float*)d_out;
    float* out_cnt = out + (size_t)T_DIM * TRACE * CTX * 2;

    const size_t tab_elems = (size_t)T_DIM * 64;       // 262144 per table
    const size_t need = 3 * tab_elems * sizeof(float); // 3 MB

    if (ws_size >= need) {
        float* tcos = (float*)d_ws;
        float* tsin = tcos + tab_elems;
        float* tdec = tsin + tab_elems;

        ffm_tables<<<T_DIM * 64 / 256, 256, 0, stream>>>(
            a, b, iv, jv, tcos, tsin, tdec, out_cnt);
        ffm_main<<<T_DIM, 256, 0, stream>>>(
            state_re, state_im, x_re, x_im, tcos, tsin, tdec, out);
    } else {
        ffm_kernel_fallback<<<T_DIM, 256, 0, stream>>>(
            state_re, state_im, x_re, x_im, a, b, iv, jv, out, out_cnt);
    }
}